// Round 11
// baseline (50.335 us; speedup 1.0000x reference)
//
#include <hip/hip_runtime.h>
#include <cstdint>
#include <cstddef>

typedef unsigned short u16;
typedef __attribute__((ext_vector_type(8))) short short8;
typedef __attribute__((ext_vector_type(4))) float f32x4;

__device__ __forceinline__ u16 f2bf(float f){
  union { float f; unsigned u; } c; c.f = f;
  unsigned u = c.u;
  u += 0x7fffu + ((u >> 16) & 1u);   // RNE
  return (u16)(u >> 16);
}
__device__ __forceinline__ unsigned pk2(float a, float b){
  union { float f; unsigned u; } ca, cb; ca.f = a; cb.f = b;
  return ((ca.u + 0x8000u) >> 16) | ((cb.u + 0x8000u) & 0xFFFF0000u);
}

// xT2 layout: [b][row 0..65][col 0..65][128ci] bf16, interior at (h+1, w+1).
#define XB_STRIDE 557568   // 66*66*128 (u16 elements)
#define XR_STRIDE 8448     // 66*128

// wcomb layout (u16): b*147456 + ((tap*4+cq)<<12) + (co<<5) + ciq
//   where ci = cq*32 + ciq. One (tap,cq) slab = 128co x 32ci = 8KB, linear;
//   quarters (tap,2h) and (tap,2h+1) are adjacent -> 16KB K=64 slab.

// direct-to-LDS 16B async copy
#define GLD_LDS(gsrc, ldst) \
  __builtin_amdgcn_global_load_lds((const __attribute__((address_space(1))) void*)(gsrc), \
                                   (__attribute__((address_space(3))) void*)(ldst), 16, 0, 0)

// ---------------------------------------------------------------------------
// Kernel 1: transpose x [b][128ci][4096] fp32 -> padded xT2 bf16 + SE pool
// partials. chunk==0 blocks also zero xT2[b]'s halo ring.
// 1D grid 512, b = bid&15 (bid%8 == b%8 -> L2 homing).
// ---------------------------------------------------------------------------
__global__ __launch_bounds__(256) void xpose_pool(
    const float* __restrict__ x, u16* __restrict__ xT2, float* __restrict__ part)
{
  const int bid = blockIdx.x;
  const int b = bid & 15, chunk = bid >> 4;
  const int pos0 = chunk << 7;
  const int tid = threadIdx.x;
  __shared__ u16 tile[16384];        // 32 KB, swizzled [row][g'][8ci]
  __shared__ float psum[128 * 33];
  const float* xb = x + ((size_t)b << 19) + pos0;
  const int p4 = (tid & 31) << 2;
  const int swz = (tid & 31) & 7;

  if (chunk == 0){                   // fused halo zeroing (disjoint from interior)
    u16* xh = xT2 + (size_t)b * XB_STRIDE;
    for (int i = tid; i < 4160; i += 256){     // 260 pos * 16 granules
      const int p = i >> 4, oct = i & 15;
      int row, col;
      if (p < 66)      { row = 0;        col = p; }
      else if (p < 132){ row = 65;       col = p - 66; }
      else if (p < 196){ row = p - 131;  col = 0; }
      else             { row = p - 195;  col = 65; }
      *(uint4*)(xh + row * XR_STRIDE + (col << 7) + (oct << 3)) =
          make_uint4(0u, 0u, 0u, 0u);
    }
  }

  #pragma unroll
  for (int i = 0; i < 2; ++i){
    const int gci = (tid >> 5) + (i << 3);
    const int ci8 = gci << 3;
    float4 L[8];
    #pragma unroll
    for (int j = 0; j < 8; ++j)
      L[j] = *(const float4*)(xb + ((size_t)(ci8 + j) << 12) + p4);
    #pragma unroll
    for (int j = 0; j < 8; ++j)
      psum[(ci8 + j) * 33 + (tid & 31)] = L[j].x + L[j].y + L[j].z + L[j].w;
    const int gs = gci ^ swz;
    const float* e = (const float*)L;
    #pragma unroll
    for (int p = 0; p < 4; ++p){
      const int row = p4 + p;
      uint4 V;
      V.x = pk2(e[0 * 4 + p], e[1 * 4 + p]);
      V.y = pk2(e[2 * 4 + p], e[3 * 4 + p]);
      V.z = pk2(e[4 * 4 + p], e[5 * 4 + p]);
      V.w = pk2(e[6 * 4 + p], e[7 * 4 + p]);
      *(uint4*)(tile + (row << 7) + (gs << 3)) = V;
    }
  }
  __syncthreads();

  if (tid < 128){
    float s = 0.f;
    #pragma unroll 8
    for (int j = 0; j < 32; ++j) s += psum[tid * 33 + j];
    part[((b << 5) + chunk) * 128 + tid] = s;
  }

  u16* xo = xT2 + (size_t)b * XB_STRIDE;
  const int g = tid & 15, rb = (tid >> 4) << 3;
  #pragma unroll
  for (int r = 0; r < 8; ++r){
    const int row = rb + r;
    const int gs = g ^ ((row >> 2) & 7);
    uint4 v = *(const uint4*)(tile + (row << 7) + (gs << 3));
    const int pos = pos0 + row;
    const int h = pos >> 6, w = pos & 63;
    *(uint4*)(xo + (h + 1) * XR_STRIDE + ((w + 1) << 7) + (g << 3)) = v;
  }
}

// ---------------------------------------------------------------------------
// Kernel 2 (v10): combine + INLINE attn (attn_fc kernel fused away).
// grid 1024 = cp(64 co-pairs)*16 + b (bid%8==b%8 -> homing). While the W
// gld_lds staging flies, the block recomputes attn[b] from part (redundant
// but tiny). Then LDS-compute (stride-9, 9 coprime 32 -> conflict-free),
// writes linear quarter-major wcomb.
// ---------------------------------------------------------------------------
__global__ __launch_bounds__(256) void combine(
    const float* __restrict__ W, const float* __restrict__ bias,
    const float* __restrict__ part, const float* __restrict__ w1,
    const float* __restrict__ w2, const float* __restrict__ b2,
    u16* __restrict__ wcomb, float* __restrict__ bcomb)
{
  __shared__ float wlds[9216];   // [k][co_l][1152]
  __shared__ float sp[128];
  __shared__ float sh[33];
  __shared__ float sat[4];
  const int bid = blockIdx.x;
  const int b = bid & 15, cp = bid >> 4;    // cp: co-pair 0..63
  const int tid = threadIdx.x;

  // stage W[k][cp*2+co_l][:] : 2304 granules of 16B (async; hides under attn)
  #pragma unroll
  for (int it = 0; it < 9; ++it){
    const int G = it * 256 + tid;
    const int k = G / 576, rem = G - k * 576;
    const int co_l = rem / 288, j4 = rem - co_l * 288;
    const float* src = W + (size_t)(k * 128 + (cp << 1) + co_l) * 1152 + (j4 << 2);
    GLD_LDS(src, (char*)wlds + (G << 4));
  }

  // ---- inline attn[b]: pool -> fc1 -> relu -> fc2 -> softmax(/30) ----
  if (tid < 128){
    const float* pb = part + (b << 12);
    float s = 0.f;
    #pragma unroll 8
    for (int c = 0; c < 32; ++c) s += pb[(c << 7) + tid];
    sp[tid] = s * (1.f / 4096.f);
  }
  __syncthreads();
  if (tid < 33){
    float h = 0.f;
    for (int ci = 0; ci < 128; ++ci) h += sp[ci] * w1[tid * 128 + ci];
    sh[tid] = fmaxf(h, 0.f);
  }
  __syncthreads();
  if (tid == 0){
    float l[4];
    #pragma unroll
    for (int t = 0; t < 4; ++t){
      float v = b2[t];
      for (int j = 0; j < 33; ++j) v += sh[j] * w2[t * 33 + j];
      l[t] = v * (1.f / 30.f);
    }
    float m = fmaxf(fmaxf(l[0], l[1]), fmaxf(l[2], l[3]));
    float e0 = __expf(l[0] - m), e1 = __expf(l[1] - m);
    float e2 = __expf(l[2] - m), e3 = __expf(l[3] - m);
    float inv = 1.f / (e0 + e1 + e2 + e3);
    sat[0] = e0 * inv; sat[1] = e1 * inv; sat[2] = e2 * inv; sat[3] = e3 * inv;
  }
  asm volatile("s_waitcnt vmcnt(0)" ::: "memory");
  __syncthreads();
  const float a0 = sat[0], a1 = sat[1], a2 = sat[2], a3 = sat[3];

  if (tid < 2){
    const int co = (cp << 1) + tid;
    bcomb[(b << 7) + co] = a0 * bias[co] + a1 * bias[128 + co]
                         + a2 * bias[256 + co] + a3 * bias[384 + co];
  }

  u16* wob = wcomb + (size_t)b * 147456;
  for (int gi = tid; gi < 288; gi += 256){  // 2co * 9tap * (4cq*4g) granules
    const int co_l = gi / 144;
    const int r = gi - co_l * 144;
    const int tap = r >> 4;
    const int gg = r & 15;
    const int cq = gg >> 2, g = gg & 3;
    const int co = (cp << 1) + co_l;
    union { u16 h[8]; uint4 v; } pk;
    #pragma unroll
    for (int e = 0; e < 8; ++e){
      const int ci = (cq << 5) + (g << 3) + e;
      const int j = ci * 9 + tap;
      float s = a0 * wlds[co_l * 1152 + j]        + a1 * wlds[2304 + co_l * 1152 + j]
              + a2 * wlds[4608 + co_l * 1152 + j] + a3 * wlds[6912 + co_l * 1152 + j];
      pk.h[e] = f2bf(s);
    }
    *(uint4*)(wob + (((tap << 2) + cq) << 12) + (co << 5) + (g << 3)) = pk.v;
  }
}

// ---------------------------------------------------------------------------
// Kernel 3 (v10): ci-HALF implicit GEMM, K=64 per step -> 18 steps (half the
// sync points of v9b). x-half (4row x 66col x 64ci = 33.8KB) staged once per
// 9 taps (2 restages total); 16KB W slabs (2 adjacent quarter-slabs) stream
// dbuf'd (4 loads/thr). Per step 32 MFMA/wave vs one vmcnt+barrier.
// Bank-conflict-free via slot ^= (col&1)<<2 on x (pre-permuted global src +
// same XOR on read). LDS 33792 + 2x16384 = 66560B -> 2 blocks/CU.
// grid 512 x 256 thr (4 waves: wr=h-row, wcv=co-half), b homed to XCD b%8.
// ---------------------------------------------------------------------------
__global__ __launch_bounds__(256, 2) void conv_mfma(
    const u16* __restrict__ xT2, const u16* __restrict__ wcomb,
    const float* __restrict__ bcomb, float* __restrict__ out)
{
  extern __shared__ char smem[];
  u16* s_x = (u16*)smem;               // [4row][66col][8slot][8ci] = 33792B
  u16* s_w = (u16*)(smem + 33792);     // 2 bufs x 8192 u16 ([cq][co][32])

  const int tid = threadIdx.x;
  const int lane = tid & 63, wid = tid >> 6;
  const int wr = wid & 1, wcv = wid >> 1;    // wr: h-row, wcv: co-half
  const int l15 = lane & 15, hi = lane >> 4;

  const int bid = blockIdx.x;
  const int b = bid & 15;                    // bid%8 == b%8 (L2 homing)
  const int h0 = (bid >> 4) << 1;            // 2 output rows

  const u16* Abase = wcomb + (size_t)b * 147456;
  const u16* Xbase = xT2 + (size_t)b * XB_STRIDE;

  // stage x half HF: 2112 granules; LDS slot s holds global k-granule
  // s ^ ((col&1)<<2)  (read undoes it).
#define STAGE_X(HF) { \
    _Pragma("unroll") \
    for (int _it = 0; _it < 9; ++_it){ \
      const int _G = _it * 256 + tid; \
      if (_it < 8 || _G < 2112){ \
        const int _slot = _G & 7, _t = _G >> 3; \
        const int _col = _t % 66, _row = _t / 66; \
        const u16* _src = Xbase + (h0 + _row) * XR_STRIDE + (_col << 7) \
                        + ((HF) << 6) + ((_slot ^ ((_col & 1) << 2)) << 3); \
        GLD_LDS(_src, s_x + (_G << 3)); \
      } \
    } }

  // stage K=64 W slab (quarters 2*HF, 2*HF+1 of TAP): 1024 granules, linear.
#define STAGE_W(HF, TAP, BUF) { \
    const u16* _As = Abase + ((((TAP) << 2) + ((HF) << 1)) << 12); \
    u16* _sw = s_w + (BUF) * 8192; \
    _Pragma("unroll") \
    for (int _it = 0; _it < 4; ++_it){ \
      const int _G = _it * 256 + tid; \
      GLD_LDS(_As + (_G << 3), _sw + (_G << 3)); \
    } }

#define COMPUTE(TAP, BUF) { \
    const int _dh = (TAP) / 3, _dw = (TAP) - 3 * (_dh); \
    const u16* _sw = s_w + (BUF) * 8192; \
    _Pragma("unroll") \
    for (int _ks = 0; _ks < 2; ++_ks){ \
      short8 _af[4], _bf[4]; \
      _Pragma("unroll") \
      for (int _a = 0; _a < 4; ++_a){ \
        const int _co = (wcv << 6) + (_a << 4) + l15; \
        _af[_a] = *(const short8*)(_sw + (_ks << 12) + (_co << 5) + (hi << 3)); \
      } \
      _Pragma("unroll") \
      for (int _p = 0; _p < 4; ++_p){ \
        const int _col = l15 + _dw + (_p << 4); \
        const int _sl = ((_ks << 2) + hi) ^ ((_col & 1) << 2); \
        _bf[_p] = *(const short8*)(s_x + ((((wr + _dh) * 66 + _col) << 6) + (_sl << 3))); \
      } \
      _Pragma("unroll") \
      for (int _a = 0; _a < 4; ++_a) \
        _Pragma("unroll") \
        for (int _p = 0; _p < 4; ++_p) \
          acc[_a][_p] = __builtin_amdgcn_mfma_f32_16x16x32_bf16(_af[_a], _bf[_p], acc[_a][_p], 0, 0, 0); \
    } }

#define VM0_BAR { asm volatile("s_waitcnt vmcnt(0)" ::: "memory"); __syncthreads(); }

  f32x4 acc[4][4] = {};

  STAGE_X(0);
  STAGE_W(0, 0, 0);
  VM0_BAR;

  int buf = 0;
  for (int hf = 0; hf < 2; ++hf){
    #pragma unroll
    for (int tap = 0; tap < 9; ++tap){
      if (!(hf == 1 && tap == 8)){
        const int nh = (tap == 8) ? 1 : hf;
        const int nt = (tap == 8) ? 0 : tap + 1;
        STAGE_W(nh, nt, buf ^ 1);
      }
      COMPUTE(tap, buf);
      VM0_BAR;
      buf ^= 1;
      if (tap == 8 && hf == 0){
        STAGE_X(1);
        VM0_BAR;
      }
    }
  }

#undef VM0_BAR
#undef COMPUTE
#undef STAGE_W
#undef STAGE_X

  // ---- epilogue: C/D col=l15 (w), row=hi*4+r (co). NT stores. ----
  const int hrow = h0 + wr;
  float* ob = out + ((size_t)b << 19) + (hrow << 6) + l15;
  #pragma unroll
  for (int a = 0; a < 4; ++a){
    const int co0 = (wcv << 6) + (a << 4) + (hi << 2);
    #pragma unroll
    for (int r = 0; r < 4; ++r){
      const float bc = bcomb[(b << 7) + co0 + r];
      float* op = ob + (size_t)(co0 + r) * 4096;
      #pragma unroll
      for (int p = 0; p < 4; ++p)
        __builtin_nontemporal_store(acc[a][p][r] + bc, op + (p << 4));
    }
  }
}

// ---------------------------------------------------------------------------
extern "C" void kernel_launch(void* const* d_in, const int* in_sizes, int n_in,
                              void* d_out, int out_size, void* d_ws, size_t ws_size,
                              hipStream_t stream)
{
  const float* x    = (const float*)d_in[0];
  const float* W    = (const float*)d_in[1];
  const float* bias = (const float*)d_in[2];
  const float* w1   = (const float*)d_in[3];
  const float* w2   = (const float*)d_in[4];
  const float* b2   = (const float*)d_in[5];
  float* out = (float*)d_out;

  char* ws = (char*)d_ws;
  float* part  = (float*)(ws);               // 262144 B
  float* bcomb = (float*)(ws + 262144);      // 8192 B
  u16*   xT2   = (u16*)  (ws + 270592);      // 17,842,176 B
  u16*   wcomb = (u16*)  (ws + 18112768);    // 4,718,592 B (end ~22.8 MB)

  xpose_pool<<<512, 256, 0, stream>>>(x, xT2, part);
  combine<<<1024, 256, 0, stream>>>(W, bias, part, w1, w2, b2, wcomb, bcomb);

  (void)hipFuncSetAttribute(reinterpret_cast<const void*>(conv_mfma),
                            hipFuncAttributeMaxDynamicSharedMemorySize, 66560);
  conv_mfma<<<512, 256, 66560, stream>>>(xT2, wcomb, bcomb, out);
}

// Round 12
// 49.266 us; speedup vs baseline: 1.0217x; 1.0217x over previous
//
#include <hip/hip_runtime.h>
#include <cstdint>
#include <cstddef>

typedef unsigned short u16;
typedef __attribute__((ext_vector_type(8))) short short8;
typedef __attribute__((ext_vector_type(4))) float f32x4;

__device__ __forceinline__ u16 f2bf(float f){
  union { float f; unsigned u; } c; c.f = f;
  unsigned u = c.u;
  u += 0x7fffu + ((u >> 16) & 1u);   // RNE
  return (u16)(u >> 16);
}
__device__ __forceinline__ unsigned pk2(float a, float b){
  union { float f; unsigned u; } ca, cb; ca.f = a; cb.f = b;
  return ((ca.u + 0x8000u) >> 16) | ((cb.u + 0x8000u) & 0xFFFF0000u);
}

// xT2 layout: [b][row 0..65][col 0..65][128ci] bf16, interior at (h+1, w+1).
#define XB_STRIDE 557568   // 66*66*128 (u16 elements)
#define XR_STRIDE 8448     // 66*128

// wcomb layout (u16): b*147456 + ((tap*4+q)<<12) + (co<<5) + ciq
//   where ci = q*32 + ciq. One (tap,q) slab = 128co x 32ci = 8KB, linear.

// direct-to-LDS 16B async copy
#define GLD_LDS(gsrc, ldst) \
  __builtin_amdgcn_global_load_lds((const __attribute__((address_space(1))) void*)(gsrc), \
                                   (__attribute__((address_space(3))) void*)(ldst), 16, 0, 0)

// raw barrier WITHOUT the implicit vmcnt(0) drain of __syncthreads()
#define BAR { asm volatile("s_waitcnt lgkmcnt(0)" ::: "memory"); \
              __builtin_amdgcn_s_barrier(); }
#define WAIT_VM(N) asm volatile("s_waitcnt vmcnt(" #N ")" ::: "memory")

// ---------------------------------------------------------------------------
// Kernel 1 (v12): transpose x -> padded xT2 bf16 + SE pool partials.
// 64-pos chunks: grid 1024 (4 blocks/CU), b = bid&15 (bid%8==b%8 homing).
// tile 64row x 16gran x 8ci (16KB), swizzle gs = g ^ ((row>>2)&7) both sides
// (8 lanes per bank-quad on write and read -> conflict-free b128).
// ---------------------------------------------------------------------------
__global__ __launch_bounds__(256) void xpose_pool(
    const float* __restrict__ x, u16* __restrict__ xT2, float* __restrict__ part)
{
  const int bid = blockIdx.x;
  const int b = bid & 15, chunk = bid >> 4;   // chunk 0..63
  const int pos0 = chunk << 6;
  const int tid = threadIdx.x;
  __shared__ u16 tile[8192];         // 16 KB
  __shared__ float psum[128 * 17];   // 8.7 KB
  const float* xb = x + ((size_t)b << 19) + pos0;
  const int rq = tid & 15;           // row-quad
  const int p4 = rq << 2;
  const int gci = tid >> 4;          // granule 0..15

  if (chunk == 0){                   // fused halo zeroing (disjoint from interior)
    u16* xh = xT2 + (size_t)b * XB_STRIDE;
    for (int i = tid; i < 4160; i += 256){     // 260 pos * 16 granules
      const int p = i >> 4, oct = i & 15;
      int row, col;
      if (p < 66)      { row = 0;        col = p; }
      else if (p < 132){ row = 65;       col = p - 66; }
      else if (p < 196){ row = p - 131;  col = 0; }
      else             { row = p - 195;  col = 65; }
      *(uint4*)(xh + row * XR_STRIDE + (col << 7) + (oct << 3)) =
          make_uint4(0u, 0u, 0u, 0u);
    }
  }

  {
    const int ci8 = gci << 3;
    float4 L[8];
    #pragma unroll
    for (int j = 0; j < 8; ++j)
      L[j] = *(const float4*)(xb + ((size_t)(ci8 + j) << 12) + p4);
    #pragma unroll
    for (int j = 0; j < 8; ++j)
      psum[(ci8 + j) * 17 + rq] = L[j].x + L[j].y + L[j].z + L[j].w;
    const int gs = gci ^ (rq & 7);   // (row>>2)&7 == rq for rows p4..p4+3
    const float* e = (const float*)L;
    #pragma unroll
    for (int p = 0; p < 4; ++p){
      const int row = p4 + p;
      uint4 V;
      V.x = pk2(e[0 * 4 + p], e[1 * 4 + p]);
      V.y = pk2(e[2 * 4 + p], e[3 * 4 + p]);
      V.z = pk2(e[4 * 4 + p], e[5 * 4 + p]);
      V.w = pk2(e[6 * 4 + p], e[7 * 4 + p]);
      *(uint4*)(tile + (row << 7) + (gs << 3)) = V;
    }
  }
  __syncthreads();

  if (tid < 128){
    float s = 0.f;
    #pragma unroll
    for (int j = 0; j < 16; ++j) s += psum[tid * 17 + j];
    part[(((b << 6) | chunk) << 7) + tid] = s;
  }

  u16* xo = xT2 + (size_t)b * XB_STRIDE;
  const int g = tid & 15, rb = (tid >> 4) << 2;
  #pragma unroll
  for (int r = 0; r < 4; ++r){
    const int row = rb + r;
    const int gs = g ^ ((row >> 2) & 7);
    uint4 v = *(const uint4*)(tile + (row << 7) + (gs << 3));
    const int pos = pos0 + row;
    const int h = pos >> 6, w = pos & 63;
    *(uint4*)(xo + (h + 1) * XR_STRIDE + ((w + 1) << 7) + (g << 3)) = v;
  }
}

// ---------------------------------------------------------------------------
// Kernel 2: combine + inline attn. grid 1024 = cp(64 co-pairs)*16 + b
// (bid%8==b%8 homing). W slice staged via gld_lds under the attn compute;
// LDS-compute (stride-9, conflict-free); linear quarter-major wcomb out.
// ---------------------------------------------------------------------------
__global__ __launch_bounds__(256) void combine(
    const float* __restrict__ W, const float* __restrict__ bias,
    const float* __restrict__ part, const float* __restrict__ w1,
    const float* __restrict__ w2, const float* __restrict__ b2,
    u16* __restrict__ wcomb, float* __restrict__ bcomb)
{
  __shared__ float wlds[9216];   // [k][co_l][1152]
  __shared__ float sp[128];
  __shared__ float sh[33];
  __shared__ float sat[4];
  const int bid = blockIdx.x;
  const int b = bid & 15, cp = bid >> 4;    // cp: co-pair 0..63
  const int tid = threadIdx.x;

  #pragma unroll
  for (int it = 0; it < 9; ++it){
    const int G = it * 256 + tid;
    const int k = G / 576, rem = G - k * 576;
    const int co_l = rem / 288, j4 = rem - co_l * 288;
    const float* src = W + (size_t)(k * 128 + (cp << 1) + co_l) * 1152 + (j4 << 2);
    GLD_LDS(src, (char*)wlds + (G << 4));
  }

  // ---- inline attn[b]: pool (64 chunks) -> fc1 -> relu -> fc2 -> softmax ----
  if (tid < 128){
    const float* pb = part + (b << 13);
    float s = 0.f;
    #pragma unroll 8
    for (int c = 0; c < 64; ++c) s += pb[(c << 7) + tid];
    sp[tid] = s * (1.f / 4096.f);
  }
  __syncthreads();
  if (tid < 33){
    float h = 0.f;
    for (int ci = 0; ci < 128; ++ci) h += sp[ci] * w1[tid * 128 + ci];
    sh[tid] = fmaxf(h, 0.f);
  }
  __syncthreads();
  if (tid == 0){
    float l[4];
    #pragma unroll
    for (int t = 0; t < 4; ++t){
      float v = b2[t];
      for (int j = 0; j < 33; ++j) v += sh[j] * w2[t * 33 + j];
      l[t] = v * (1.f / 30.f);
    }
    float m = fmaxf(fmaxf(l[0], l[1]), fmaxf(l[2], l[3]));
    float e0 = __expf(l[0] - m), e1 = __expf(l[1] - m);
    float e2 = __expf(l[2] - m), e3 = __expf(l[3] - m);
    float inv = 1.f / (e0 + e1 + e2 + e3);
    sat[0] = e0 * inv; sat[1] = e1 * inv; sat[2] = e2 * inv; sat[3] = e3 * inv;
  }
  asm volatile("s_waitcnt vmcnt(0)" ::: "memory");
  __syncthreads();
  const float a0 = sat[0], a1 = sat[1], a2 = sat[2], a3 = sat[3];

  if (tid < 2){
    const int co = (cp << 1) + tid;
    bcomb[(b << 7) + co] = a0 * bias[co] + a1 * bias[128 + co]
                         + a2 * bias[256 + co] + a3 * bias[384 + co];
  }

  u16* wob = wcomb + (size_t)b * 147456;
  for (int gi = tid; gi < 288; gi += 256){  // 2co * 9tap * (4q*4g) granules
    const int co_l = gi / 144;
    const int r = gi - co_l * 144;
    const int tap = r >> 4;
    const int gg = r & 15;
    const int q = gg >> 2, g = gg & 3;
    const int co = (cp << 1) + co_l;
    union { u16 h[8]; uint4 v; } pk;
    #pragma unroll
    for (int e = 0; e < 8; ++e){
      const int ci = (q << 5) + (g << 3) + e;
      const int j = ci * 9 + tap;
      float s = a0 * wlds[co_l * 1152 + j]        + a1 * wlds[2304 + co_l * 1152 + j]
              + a2 * wlds[4608 + co_l * 1152 + j] + a3 * wlds[6912 + co_l * 1152 + j];
      pk.h[e] = f2bf(s);
    }
    *(uint4*)(wob + (((tap << 2) + q) << 12) + (co << 5) + (g << 3)) = pk.v;
  }
}

// ---------------------------------------------------------------------------
// Kernel 3 (v12): ci-quarter implicit GEMM with T4 counted-vmcnt pipeline +
// raw barriers (no implicit vmcnt(0) drain) + T5 setprio around MFMA.
// 36 steps (q 0..3 x tap 0..8); W: 3 x 8KB bufs, staged 2 steps ahead,
// waited with vmcnt(2) (leaves next slab's 2 loads in flight). X-quarter
// (4row x 66col x 32ci = 16.9KB) restaged at q boundaries; its 9 loads fold
// into the same vmcnt(2) at the next step top. LDS 41472B -> 2 blocks/CU.
// Addressing identical to r10-verified v9b. grid 512 x 256 thr, b homed b%8.
// ---------------------------------------------------------------------------
__global__ __launch_bounds__(256, 2) void conv_mfma(
    const u16* __restrict__ xT2, const u16* __restrict__ wcomb,
    const float* __restrict__ bcomb, float* __restrict__ out)
{
  extern __shared__ char smem[];
  u16* s_x = (u16*)smem;               // [4row][66col][4oct][8ci] = 16896B
  u16* s_w = (u16*)(smem + 16896);     // 3 bufs x 4096 u16 (8KB slabs)

  const int tid = threadIdx.x;
  const int lane = tid & 63, wid = tid >> 6;
  const int wr = wid & 1, wcv = wid >> 1;    // wr: h-row, wcv: co-half
  const int l15 = lane & 15, hi = lane >> 4;

  const int bid = blockIdx.x;
  const int b = bid & 15;                    // bid%8 == b%8 (L2 homing)
  const int h0 = (bid >> 4) << 1;            // 2 output rows

  const u16* Abase = wcomb + (size_t)b * 147456;
  const u16* Xbase = xT2 + (size_t)b * XB_STRIDE;

#define STAGE_X(Q) { \
    _Pragma("unroll") \
    for (int _it = 0; _it < 5; ++_it){ \
      const int _G = _it * 256 + tid; \
      if (_it < 4 || _G < 1056){ \
        const int _oct = _G & 3, _t = _G >> 2; \
        const int _col = _t % 66, _row = _t / 66; \
        const u16* _src = Xbase + (h0 + _row) * XR_STRIDE + (_col << 7) \
                        + ((Q) << 5) + (_oct << 3); \
        GLD_LDS(_src, s_x + (_G << 3)); \
      } \
    } }

#define STAGE_W(Q, TAP, BUF) { \
    const u16* _As = Abase + ((((TAP) << 2) + (Q)) << 12); \
    u16* _sw = s_w + (BUF) * 4096; \
    GLD_LDS(_As + (tid << 3), _sw + (tid << 3)); \
    GLD_LDS(_As + ((tid + 256) << 3), _sw + ((tid + 256) << 3)); }

#define COMPUTE(TAP, BUF) { \
    const int _dh = (TAP) / 3, _dw = (TAP) - 3 * (_dh); \
    const u16* _sw = s_w + (BUF) * 4096; \
    short8 _af[4], _bf[4]; \
    _Pragma("unroll") \
    for (int _a = 0; _a < 4; ++_a){ \
      const int _co = (wcv << 6) + (_a << 4) + l15; \
      _af[_a] = *(const short8*)(_sw + (_co << 5) + (hi << 3)); \
    } \
    _Pragma("unroll") \
    for (int _p = 0; _p < 4; ++_p){ \
      const int _col = l15 + _dw + (_p << 4); \
      _bf[_p] = *(const short8*)(s_x + (((wr + _dh) * 66 + _col) << 5) + (hi << 3)); \
    } \
    _Pragma("unroll") \
    for (int _a = 0; _a < 4; ++_a) \
      _Pragma("unroll") \
      for (int _p = 0; _p < 4; ++_p) \
        acc[_a][_p] = __builtin_amdgcn_mfma_f32_16x16x32_bf16(_af[_a], _bf[_p], acc[_a][_p], 0, 0, 0); }

  f32x4 acc[4][4] = {};

  // prologue: X(0) + W slabs for steps 0,1 in flight
  STAGE_X(0);
  STAGE_W(0, 0, 0);
  STAGE_W(0, 1, 1);

  for (int q = 0; q < 4; ++q){
    #pragma unroll
    for (int tap = 0; tap < 9; ++tap){
      // wait: slab(step) [+ X at q boundary] done; leave newest 2 in flight
      if (tap == 8 && q == 3){ WAIT_VM(0); } else { WAIT_VM(2); }
      BAR;
      // prefetch slab(step+2) into the buffer freed by compute(step-1)
      if (tap <= 6){
        STAGE_W(q, tap + 2, (tap + 2) % 3);
      } else if (tap == 7){
        if (q < 3){ STAGE_W(q + 1, 0, 0); }
      }
      __builtin_amdgcn_s_setprio(1);
      COMPUTE(tap, tap % 3);
      __builtin_amdgcn_s_setprio(0);
      if (tap == 8 && q < 3){
        BAR;                   // all waves done reading s_x(q)
        STAGE_X(q + 1);        // 9 loads; waited at next step's vmcnt(2)
        STAGE_W(q + 1, 1, 1);  // slab(step+2), buf (8+2)%3 = 1
      }
    }
  }

#undef COMPUTE
#undef STAGE_W
#undef STAGE_X

  // ---- epilogue: C/D col=l15 (w), row=hi*4+r (co). NT stores. ----
  const int hrow = h0 + wr;
  float* ob = out + ((size_t)b << 19) + (hrow << 6) + l15;
  #pragma unroll
  for (int a = 0; a < 4; ++a){
    const int co0 = (wcv << 6) + (a << 4) + (hi << 2);
    #pragma unroll
    for (int r = 0; r < 4; ++r){
      const float bc = bcomb[(b << 7) + co0 + r];
      float* op = ob + (size_t)(co0 + r) * 4096;
      #pragma unroll
      for (int p = 0; p < 4; ++p)
        __builtin_nontemporal_store(acc[a][p][r] + bc, op + (p << 4));
    }
  }
}

// ---------------------------------------------------------------------------
extern "C" void kernel_launch(void* const* d_in, const int* in_sizes, int n_in,
                              void* d_out, int out_size, void* d_ws, size_t ws_size,
                              hipStream_t stream)
{
  const float* x    = (const float*)d_in[0];
  const float* W    = (const float*)d_in[1];
  const float* bias = (const float*)d_in[2];
  const float* w1   = (const float*)d_in[3];
  const float* w2   = (const float*)d_in[4];
  const float* b2   = (const float*)d_in[5];
  float* out = (float*)d_out;

  char* ws = (char*)d_ws;
  float* part  = (float*)(ws);               // 16*64*128*4 = 524288 B
  float* bcomb = (float*)(ws + 524288);      // 8192 B
  u16*   xT2   = (u16*)  (ws + 532480);      // 17,842,176 B
  u16*   wcomb = (u16*)  (ws + 18374656);    // 4,718,592 B (end ~23.1 MB)

  xpose_pool<<<1024, 256, 0, stream>>>(x, xT2, part);
  combine<<<1024, 256, 0, stream>>>(W, bias, part, w1, w2, b2, wcomb, bcomb);

  (void)hipFuncSetAttribute(reinterpret_cast<const void*>(conv_mfma),
                            hipFuncAttributeMaxDynamicSharedMemorySize, 41472);
  conv_mfma<<<512, 256, 41472, stream>>>(xT2, wcomb, bcomb, out);
}